// Round 6
// baseline (1136.586 us; speedup 1.0000x reference)
//
#include <hip/hip_runtime.h>
#include <hip/hip_fp16.h>

// GNN: fc1 -> GCNConv x2 -> mean-pool -> L2norm -> fc2
// N=100000, E=1.6M, F=H=128, O=64, G=1024.
// R6: CSC PUSH aggregation. Pull's 410MB of latency-bound random gathers
// (each hW row read ~16x) replaced by: stream hW once (src-ordered, 25.6MB)
// + fire-and-forget global_atomic_pk_add_f16 scatter (410MB no-return
// atomics, no load-latency chain). Self-term fused into GEMM epilogue
// (dual write: hW + inv-scaled accumulator init). Bias+PReLU(+pool) as
// streaming epilogue. MFMA GEMMs unchanged from R5.

#define CHK 1024  // scan chunk size
typedef unsigned int u32;
using f16 = _Float16;
using f16x8 = __attribute__((ext_vector_type(8))) _Float16;
using f32x4 = __attribute__((ext_vector_type(4))) float;

__device__ inline void atomic_pk_add_h2(__half2* addr, __half2 val) {
  asm volatile("global_atomic_pk_add_f16 %0, %1, off"
               :: "v"(addr), "v"(val) : "memory");
}

__global__ __launch_bounds__(256) void k_hist(const int* __restrict__ src,
                                              const int* __restrict__ dst,
                                              const float* __restrict__ w,
                                              int* __restrict__ cnt,
                                              float* __restrict__ degf, int E) {
  int e = blockIdx.x * 256 + threadIdx.x;
  if (e < E) {
    atomicAdd(&cnt[src[e]], 1);      // out-degree (CSC by src)
    atomicAdd(&degf[dst[e]], w[e]);  // weighted in-degree (normalization)
  }
}

__global__ __launch_bounds__(256) void k_dis(const float* __restrict__ degf,
                                             float* __restrict__ dis,
                                             float* __restrict__ inv, int N) {
  int n = blockIdx.x * 256 + threadIdx.x;
  if (n < N) {
    float deg = degf[n] + 1.0f;  // self-loop weight 1
    dis[n] = rsqrtf(deg);
    inv[n] = 1.0f / deg;
  }
}

__global__ __launch_bounds__(256) void k_scan_reduce(const int* __restrict__ cnt,
                                                     int* __restrict__ chunkSum, int N) {
  __shared__ int sd[256];
  int b = blockIdx.x, t = threadIdx.x;
  int base = b * CHK + t * 4;
  int s = 0;
#pragma unroll
  for (int i = 0; i < 4; i++)
    if (base + i < N) s += cnt[base + i];
  sd[t] = s;
  __syncthreads();
  for (int off = 128; off; off >>= 1) {
    if (t < off) sd[t] += sd[t + off];
    __syncthreads();
  }
  if (t == 0) chunkSum[b] = sd[0];
}

__global__ void k_scan_chunks(const int* __restrict__ chunkSum,
                              int* __restrict__ chunkOff, int NC) {
  if (threadIdx.x == 0 && blockIdx.x == 0) {
    int s = 0;
    for (int i = 0; i < NC; i++) {
      chunkOff[i] = s;
      s += chunkSum[i];
    }
  }
}

__global__ __launch_bounds__(256) void k_scan_final(const int* __restrict__ cnt,
                                                    const int* __restrict__ chunkOff,
                                                    int* __restrict__ rowptr,
                                                    int* __restrict__ cursor, int N, int E) {
  __shared__ int sd[256];
  int b = blockIdx.x, t = threadIdx.x;
  int base = b * CHK + t * 4;
  int v[4], loc[4];
#pragma unroll
  for (int i = 0; i < 4; i++) v[i] = (base + i < N) ? cnt[base + i] : 0;
  loc[0] = 0;
  loc[1] = v[0];
  loc[2] = v[0] + v[1];
  loc[3] = v[0] + v[1] + v[2];
  int tot = loc[3] + v[3];
  sd[t] = tot;
  __syncthreads();
  for (int off = 1; off < 256; off <<= 1) {
    int xv = (t >= off) ? sd[t - off] : 0;
    __syncthreads();
    sd[t] += xv;
    __syncthreads();
  }
  int tbase = (t ? sd[t - 1] : 0) + chunkOff[b];
#pragma unroll
  for (int i = 0; i < 4; i++) {
    if (base + i < N) {
      int r = tbase + loc[i];
      rowptr[base + i] = r;
      cursor[base + i] = r;
    }
  }
  if (b == 0 && t == 0) rowptr[N] = E;
}

// CSC by src: entry = (dst, coef-bits)
__global__ __launch_bounds__(256) void k_scatter(const int* __restrict__ src,
                                                 const int* __restrict__ dst,
                                                 const float* __restrict__ w,
                                                 const float* __restrict__ dis,
                                                 int* __restrict__ cursor,
                                                 int2* __restrict__ csc, int E) {
  int e = blockIdx.x * 256 + threadIdx.x;
  if (e < E) {
    int s = src[e], d = dst[e];
    float c = w[e] * dis[s] * dis[d];
    int p = atomicAdd(&cursor[s], 1);
    int2 v;
    v.x = d;
    v.y = __float_as_int(c);
    csc[p] = v;
  }
}

// Pack W [128][128] row-major (W[o][k], fp32) into MFMA B-fragment order.
__global__ __launch_bounds__(256) void k_prep_bfrag(const float* __restrict__ W,
                                                    f16x8* __restrict__ Bf) {
  int t = blockIdx.x * 256 + threadIdx.x;  // 0..2047
  int combo = t >> 6;                      // kc*8+ct
  int l = t & 63;
  int o = (combo & 7) * 16 + (l & 15);
  int k0 = (combo >> 3) * 32 + (l >> 4) * 8;
  f16x8 b;
#pragma unroll
  for (int i = 0; i < 8; i++) b[i] = (f16)W[o * 128 + k0 + i];
  Bf[combo * 64 + l] = b;
}

// MFMA GEMM: out[n][o] = act( sum_k A[n][k]*W[o][k] (+bias) ).
// SELF: additionally write accum[n] = out[n]*inv[n] (push-accumulator init).
template <bool FP32_IN, bool BIAS, bool SELF>
__global__ __launch_bounds__(256) void k_gemm_mfma(const f16* __restrict__ Ah,
                                                   const float* __restrict__ Af,
                                                   const f16x8* __restrict__ Bf,
                                                   f16* __restrict__ out,
                                                   __half2* __restrict__ accum,
                                                   const float* __restrict__ inv,
                                                   const float* __restrict__ bias,
                                                   const float* __restrict__ slope,
                                                   int N) {
  __shared__ f16 ls[64 * 128];
  int t = threadIdx.x;
  int w = t >> 6, l = t & 63;
  int l15 = l & 15, kgrp = l >> 4;
  int nodeBase = blockIdx.x * 64 + w * 16;
  f32x4 acc[8];
#pragma unroll
  for (int ct = 0; ct < 8; ct++)
#pragma unroll
    for (int j = 0; j < 4; j++) acc[ct][j] = 0.f;

  int arow = nodeBase + l15;
  if (arow >= N) arow = N - 1;  // clamp: duplicate read, store is guarded
#pragma unroll
  for (int kc = 0; kc < 4; kc++) {
    f16x8 a;
    if (FP32_IN) {
      const float4* p0 = (const float4*)(Af + (size_t)arow * 128 + kc * 32 + kgrp * 8);
      float4 x0 = p0[0], x1 = p0[1];
      a[0] = (f16)x0.x; a[1] = (f16)x0.y; a[2] = (f16)x0.z; a[3] = (f16)x0.w;
      a[4] = (f16)x1.x; a[5] = (f16)x1.y; a[6] = (f16)x1.z; a[7] = (f16)x1.w;
    } else {
      a = *(const f16x8*)(Ah + (size_t)arow * 128 + kc * 32 + kgrp * 8);
    }
#pragma unroll
    for (int ct = 0; ct < 8; ct++) {
      f16x8 b = Bf[(kc * 8 + ct) * 64 + l];
      acc[ct] = __builtin_amdgcn_mfma_f32_16x16x32_f16(a, b, acc[ct], 0, 0, 0);
    }
  }
  // C/D layout: col=l&15, row=(l>>4)*4+j  [HW-verified m89].
  float sl = BIAS ? *slope : 0.f;
  f16* slab = ls + w * 16 * 128;
#pragma unroll
  for (int ct = 0; ct < 8; ct++) {
    float bv = BIAS ? bias[ct * 16 + l15] : 0.f;
#pragma unroll
    for (int j = 0; j < 4; j++) {
      float v = acc[ct][j];
      if (BIAS) {
        v += bv;
        v = v >= 0.f ? v : sl * v;
      }
      slab[(kgrp * 4 + j) * 128 + ct * 16 + l15] = (f16)v;
    }
  }
  __syncthreads();
  // Coalesced store: lane l -> row l>>2, chunks (l&3)+4i (16B each).
  {
    int r = l >> 2;
    int gnode = nodeBase + r;
    if (gnode < N) {
      const uint4* srcp = (const uint4*)(slab + r * 128);
      uint4* dstp = (uint4*)(out + (size_t)gnode * 128);
      __half2 iv2;
      uint4* dsto = nullptr;
      if (SELF) {
        iv2 = __float2half2_rn(inv[gnode]);
        dsto = (uint4*)(accum + (size_t)gnode * 64);
      }
#pragma unroll
      for (int i = 0; i < 4; i++) {
        int chunk = (l & 3) + i * 4;
        uint4 q = srcp[chunk];
        dstp[chunk] = q;
        if (SELF) {
          __half2* qh = (__half2*)&q;
#pragma unroll
          for (int j = 0; j < 4; j++) qh[j] = __hmul2(qh[j], iv2);
          dsto[chunk] = q;
        }
      }
    }
  }
}

// PUSH aggregation: wave per SRC node. Stream own hW row (one coalesced
// load), then for each out-edge: scale row by c and fire a no-return
// pk_add_f16 atomic into accum[dst]. No load-latency chains.
__global__ __launch_bounds__(256) void k_push(const __half2* __restrict__ hW,
                                              const int* __restrict__ rowptr,
                                              const int2* __restrict__ csc,
                                              __half2* __restrict__ accum, int N) {
  int wid = (blockIdx.x * 256 + threadIdx.x) >> 6;
  if (wid >= N) return;
  int l = threadIdx.x & 63;
  int r0 = rowptr[wid], r1 = rowptr[wid + 1];
  r0 = __builtin_amdgcn_readfirstlane(r0);
  r1 = __builtin_amdgcn_readfirstlane(r1);
  if (r0 == r1) return;
  __half2 row = hW[(u32)wid * 64u + (u32)l];
  int e = r0;
  for (; e + 4 <= r1; e += 4) {
    int2 e0 = csc[e], e1 = csc[e + 1], e2 = csc[e + 2], e3 = csc[e + 3];
    __half2 s0 = __hmul2(row, __float2half2_rn(__int_as_float(e0.y)));
    __half2 s1 = __hmul2(row, __float2half2_rn(__int_as_float(e1.y)));
    __half2 s2 = __hmul2(row, __float2half2_rn(__int_as_float(e2.y)));
    __half2 s3 = __hmul2(row, __float2half2_rn(__int_as_float(e3.y)));
    atomic_pk_add_h2(&accum[(u32)e0.x * 64u + (u32)l], s0);
    atomic_pk_add_h2(&accum[(u32)e1.x * 64u + (u32)l], s1);
    atomic_pk_add_h2(&accum[(u32)e2.x * 64u + (u32)l], s2);
    atomic_pk_add_h2(&accum[(u32)e3.x * 64u + (u32)l], s3);
  }
  for (; e < r1; ++e) {
    int2 en = csc[e];
    __half2 s = __hmul2(row, __float2half2_rn(__int_as_float(en.y)));
    atomic_pk_add_h2(&accum[(u32)en.x * 64u + (u32)l], s);
  }
}

// Streaming epilogue: v = prelu(accum + bias); write fp16 h (or pool-atomics).
template <bool POOL>
__global__ __launch_bounds__(256) void k_epi(const __half2* __restrict__ acc,
                                             const float* __restrict__ bias,
                                             const float* __restrict__ slope,
                                             const int* __restrict__ batch,
                                             __half2* __restrict__ outh,
                                             float* __restrict__ pool,
                                             float* __restrict__ cntg, int N) {
  int i = blockIdx.x * 256 + threadIdx.x;  // one half2 per thread
  if (i >= N * 64) return;
  int l = i & 63;
  float2 v = __half22float2(acc[i]);
  float a = *slope;
  float2 b = *(const float2*)&bias[l * 2];
  v.x += b.x;
  v.y += b.y;
  v.x = v.x >= 0.f ? v.x : a * v.x;
  v.y = v.y >= 0.f ? v.y : a * v.y;
  if (POOL) {
    int n = i >> 6;
    int g = batch[n];
    atomicAdd(&pool[(size_t)g * 128 + l * 2], v.x);
    atomicAdd(&pool[(size_t)g * 128 + l * 2 + 1], v.y);
    if (l == 0) atomicAdd(&cntg[g], 1.0f);
  } else {
    outh[i] = __float22half2_rn(v);
  }
}

// Per-graph: mean, L2-normalize, out = hg @ fc2_w.T + fc2_b.  1 wave/graph.
__global__ __launch_bounds__(64) void k_final(const float* __restrict__ pool,
                                              const float* __restrict__ cntg,
                                              const float* __restrict__ fc2w,
                                              const float* __restrict__ fc2b,
                                              float* __restrict__ out) {
  __shared__ float hg[128];
  int g = blockIdx.x, l = threadIdx.x;
  float cnt = cntg[g];
  float ic = 1.0f / fmaxf(cnt, 1.0f);
  float2 v = *(const float2*)&pool[(size_t)g * 128 + l * 2];
  v.x *= ic;
  v.y *= ic;
  float ss = v.x * v.x + v.y * v.y;
#pragma unroll
  for (int off = 1; off < 64; off <<= 1) ss += __shfl_xor(ss, off);
  float nrm = sqrtf(ss);
  float sc = 1.0f / fmaxf(nrm, 1e-12f);
  hg[l * 2] = v.x * sc;
  hg[l * 2 + 1] = v.y * sc;
  __syncthreads();
  float acc = fc2b[l];
#pragma unroll 4
  for (int k = 0; k < 128; k++) acc += hg[k] * fc2w[l * 128 + k];
  out[(size_t)g * 64 + l] = acc;
}

extern "C" void kernel_launch(void* const* d_in, const int* in_sizes, int n_in,
                              void* d_out, int out_size, void* d_ws, size_t ws_size,
                              hipStream_t stream) {
  const float* x = (const float*)d_in[0];
  const int* ei = (const int*)d_in[1];
  const float* ew = (const float*)d_in[2];
  const int* batch = (const int*)d_in[3];
  const float* fc1_w = (const float*)d_in[4];
  const float* fc1_b = (const float*)d_in[5];
  const float* gc1_w = (const float*)d_in[6];
  const float* gc1_b = (const float*)d_in[7];
  const float* gc2_w = (const float*)d_in[8];
  const float* gc2_b = (const float*)d_in[9];
  const float* fc2_w = (const float*)d_in[10];
  const float* fc2_b = (const float*)d_in[11];
  const float* a_fc1 = (const float*)d_in[12];
  const float* a_gc1 = (const float*)d_in[13];
  const float* a_gc2 = (const float*)d_in[14];

  int N = in_sizes[0] / 128;
  int E = in_sizes[2];
  int G = out_size / 64;
  const int* src = ei;
  const int* dst = ei + E;

  char* p = (char*)d_ws;
  auto carve = [&](size_t bytes) -> char* {
    char* r = p;
    p += (bytes + 255) & ~(size_t)255;
    return r;
  };
  f16* bufA = (f16*)carve((size_t)N * 128 * 2);        // h (fp16 rows)
  f16* bufH = (f16*)carve((size_t)N * 128 * 2);        // hW (fp16 rows)
  __half2* bufO = (__half2*)carve((size_t)N * 64 * 4); // push accumulator
  int2* csc = (int2*)carve((size_t)E * 8);             // (dst, coef-bits) by src
  int* cnt = (int*)carve((size_t)N * 4);
  int* rowptr = (int*)carve((size_t)(N + 1) * 4);
  int* cursor = (int*)carve((size_t)N * 4);
  float* degf = (float*)carve((size_t)N * 4);
  float* dis = (float*)carve((size_t)N * 4);
  float* inv = (float*)carve((size_t)N * 4);
  f16x8* Bf1 = (f16x8*)carve(2048 * 16);
  f16x8* Bf2 = (f16x8*)carve(2048 * 16);
  f16x8* Bf3 = (f16x8*)carve(2048 * 16);
  int NC = (N + CHK - 1) / CHK;
  int* chunkSum = (int*)carve((size_t)NC * 4);
  int* chunkOff = (int*)carve((size_t)NC * 4);
  float* pool = (float*)carve((size_t)G * 128 * 4);
  float* cntg = (float*)carve((size_t)G * 4);

  hipMemsetAsync(cnt, 0, (size_t)N * 4, stream);
  hipMemsetAsync(degf, 0, (size_t)N * 4, stream);
  hipMemsetAsync(pool, 0, (size_t)G * 128 * 4, stream);
  hipMemsetAsync(cntg, 0, (size_t)G * 4, stream);

  k_prep_bfrag<<<8, 256, 0, stream>>>(fc1_w, Bf1);
  k_prep_bfrag<<<8, 256, 0, stream>>>(gc1_w, Bf2);
  k_prep_bfrag<<<8, 256, 0, stream>>>(gc2_w, Bf3);

  int gE = (E + 255) / 256;
  int gN = (N + 255) / 256;
  k_hist<<<gE, 256, 0, stream>>>(src, dst, ew, cnt, degf, E);
  k_dis<<<gN, 256, 0, stream>>>(degf, dis, inv, N);
  k_scan_reduce<<<NC, 256, 0, stream>>>(cnt, chunkSum, N);
  k_scan_chunks<<<1, 64, 0, stream>>>(chunkSum, chunkOff, NC);
  k_scan_final<<<NC, 256, 0, stream>>>(cnt, chunkOff, rowptr, cursor, N, E);
  k_scatter<<<gE, 256, 0, stream>>>(src, dst, ew, dis, cursor, csc, E);

  int gGemm = (N + 63) / 64;
  int gWave = (int)(((size_t)N * 64 + 255) / 256);  // wave/node grids
  int gElem = gWave;                                // thread/half2 grids

  // h1 = prelu(x @ fc1_w.T + fc1_b) -> bufA (fp16)
  k_gemm_mfma<true, true, false><<<gGemm, 256, 0, stream>>>(
      nullptr, x, Bf1, bufA, nullptr, nullptr, fc1_b, a_fc1, N);

  // conv1: hW -> bufH, bufO = hW*inv; push edges; epi -> bufA
  k_gemm_mfma<false, false, true><<<gGemm, 256, 0, stream>>>(
      bufA, nullptr, Bf2, bufH, bufO, inv, nullptr, nullptr, N);
  k_push<<<gWave, 256, 0, stream>>>((const __half2*)bufH, rowptr, csc, bufO, N);
  k_epi<false><<<gElem, 256, 0, stream>>>(bufO, gc1_b, a_gc1, batch,
                                          (__half2*)bufA, nullptr, cntg, N);

  // conv2: hW -> bufH, bufO = hW*inv; push; epi with fused mean-pool
  k_gemm_mfma<false, false, true><<<gGemm, 256, 0, stream>>>(
      bufA, nullptr, Bf3, bufH, bufO, inv, nullptr, nullptr, N);
  k_push<<<gWave, 256, 0, stream>>>((const __half2*)bufH, rowptr, csc, bufO, N);
  k_epi<true><<<gElem, 256, 0, stream>>>(bufO, gc2_b, a_gc2, batch,
                                         nullptr, pool, cntg, N);

  k_final<<<G, 64, 0, stream>>>(pool, cntg, fc2_w, fc2_b, (float*)d_out);
}

// Round 7
// 904.922 us; speedup vs baseline: 1.2560x; 1.2560x over previous
//
#include <hip/hip_runtime.h>
#include <hip/hip_fp16.h>

// GNN: fc1 -> GCNConv x2 -> mean-pool -> L2norm -> fc2
// N=100000, E=1.6M, F=H=128, O=64, G=1024.
// R7: pull aggregation with WIDE gathers. R1/R5 showed agg time tracks
// gather-INSTRUCTION count (~1.6M), not bytes. Now 16 lanes/edge x 16B/lane
// (uint4 = 8 halfs): one instruction fetches 4 edge-rows (1KB) -> 0.4M
// instrs/conv. fp32 accum (8/lane), shfl_xor cross-group reduce, lanes 0-15
// write the row. MFMA GEMMs + CSR build unchanged from R5.

#define CHK 1024  // scan chunk size
typedef unsigned int u32;
using f16 = _Float16;
using f16x8 = __attribute__((ext_vector_type(8))) _Float16;
using f32x4 = __attribute__((ext_vector_type(4))) float;

__global__ __launch_bounds__(256) void k_hist(const int* __restrict__ dst,
                                              const float* __restrict__ w,
                                              int* __restrict__ cnt,
                                              float* __restrict__ degf, int E) {
  int e = blockIdx.x * 256 + threadIdx.x;
  if (e < E) {
    int d = dst[e];
    atomicAdd(&cnt[d], 1);
    atomicAdd(&degf[d], w[e]);
  }
}

__global__ __launch_bounds__(256) void k_dis(const float* __restrict__ degf,
                                             float* __restrict__ dis,
                                             float* __restrict__ inv, int N) {
  int n = blockIdx.x * 256 + threadIdx.x;
  if (n < N) {
    float deg = degf[n] + 1.0f;  // self-loop weight 1
    dis[n] = rsqrtf(deg);
    inv[n] = 1.0f / deg;
  }
}

__global__ __launch_bounds__(256) void k_scan_reduce(const int* __restrict__ cnt,
                                                     int* __restrict__ chunkSum, int N) {
  __shared__ int sd[256];
  int b = blockIdx.x, t = threadIdx.x;
  int base = b * CHK + t * 4;
  int s = 0;
#pragma unroll
  for (int i = 0; i < 4; i++)
    if (base + i < N) s += cnt[base + i];
  sd[t] = s;
  __syncthreads();
  for (int off = 128; off; off >>= 1) {
    if (t < off) sd[t] += sd[t + off];
    __syncthreads();
  }
  if (t == 0) chunkSum[b] = sd[0];
}

__global__ void k_scan_chunks(const int* __restrict__ chunkSum,
                              int* __restrict__ chunkOff, int NC) {
  if (threadIdx.x == 0 && blockIdx.x == 0) {
    int s = 0;
    for (int i = 0; i < NC; i++) {
      chunkOff[i] = s;
      s += chunkSum[i];
    }
  }
}

__global__ __launch_bounds__(256) void k_scan_final(const int* __restrict__ cnt,
                                                    const int* __restrict__ chunkOff,
                                                    int* __restrict__ rowptr,
                                                    int* __restrict__ cursor, int N, int E) {
  __shared__ int sd[256];
  int b = blockIdx.x, t = threadIdx.x;
  int base = b * CHK + t * 4;
  int v[4], loc[4];
#pragma unroll
  for (int i = 0; i < 4; i++) v[i] = (base + i < N) ? cnt[base + i] : 0;
  loc[0] = 0;
  loc[1] = v[0];
  loc[2] = v[0] + v[1];
  loc[3] = v[0] + v[1] + v[2];
  int tot = loc[3] + v[3];
  sd[t] = tot;
  __syncthreads();
  for (int off = 1; off < 256; off <<= 1) {
    int xv = (t >= off) ? sd[t - off] : 0;
    __syncthreads();
    sd[t] += xv;
    __syncthreads();
  }
  int tbase = (t ? sd[t - 1] : 0) + chunkOff[b];
#pragma unroll
  for (int i = 0; i < 4; i++) {
    if (base + i < N) {
      int r = tbase + loc[i];
      rowptr[base + i] = r;
      cursor[base + i] = r;
    }
  }
  if (b == 0 && t == 0) rowptr[N] = E;
}

// CSR by dst: entry = (src, coef-bits)
__global__ __launch_bounds__(256) void k_scatter(const int* __restrict__ src,
                                                 const int* __restrict__ dst,
                                                 const float* __restrict__ w,
                                                 const float* __restrict__ dis,
                                                 int* __restrict__ cursor,
                                                 int2* __restrict__ csr, int E) {
  int e = blockIdx.x * 256 + threadIdx.x;
  if (e < E) {
    int s = src[e], d = dst[e];
    float c = w[e] * dis[s] * dis[d];
    int p = atomicAdd(&cursor[d], 1);
    int2 v;
    v.x = s;
    v.y = __float_as_int(c);
    csr[p] = v;
  }
}

// Pack W [128][128] row-major (W[o][k], fp32) into MFMA B-fragment order.
__global__ __launch_bounds__(256) void k_prep_bfrag(const float* __restrict__ W,
                                                    f16x8* __restrict__ Bf) {
  int t = blockIdx.x * 256 + threadIdx.x;  // 0..2047
  int combo = t >> 6;                      // kc*8+ct
  int l = t & 63;
  int o = (combo & 7) * 16 + (l & 15);
  int k0 = (combo >> 3) * 32 + (l >> 4) * 8;
  f16x8 b;
#pragma unroll
  for (int i = 0; i < 8; i++) b[i] = (f16)W[o * 128 + k0 + i];
  Bf[combo * 64 + l] = b;
}

// MFMA GEMM: out[n][o] = act( sum_k A[n][k]*W[o][k] (+bias) ).
template <bool FP32_IN, bool BIAS>
__global__ __launch_bounds__(256) void k_gemm_mfma(const f16* __restrict__ Ah,
                                                   const float* __restrict__ Af,
                                                   const f16x8* __restrict__ Bf,
                                                   f16* __restrict__ out,
                                                   const float* __restrict__ bias,
                                                   const float* __restrict__ slope,
                                                   int N) {
  __shared__ f16 ls[64 * 128];
  int t = threadIdx.x;
  int w = t >> 6, l = t & 63;
  int l15 = l & 15, kgrp = l >> 4;
  int nodeBase = blockIdx.x * 64 + w * 16;
  f32x4 acc[8];
#pragma unroll
  for (int ct = 0; ct < 8; ct++)
#pragma unroll
    for (int j = 0; j < 4; j++) acc[ct][j] = 0.f;

  int arow = nodeBase + l15;
  if (arow >= N) arow = N - 1;  // clamp: duplicate read, store is guarded
#pragma unroll
  for (int kc = 0; kc < 4; kc++) {
    f16x8 a;
    if (FP32_IN) {
      const float4* p0 = (const float4*)(Af + (size_t)arow * 128 + kc * 32 + kgrp * 8);
      float4 x0 = p0[0], x1 = p0[1];
      a[0] = (f16)x0.x; a[1] = (f16)x0.y; a[2] = (f16)x0.z; a[3] = (f16)x0.w;
      a[4] = (f16)x1.x; a[5] = (f16)x1.y; a[6] = (f16)x1.z; a[7] = (f16)x1.w;
    } else {
      a = *(const f16x8*)(Ah + (size_t)arow * 128 + kc * 32 + kgrp * 8);
    }
#pragma unroll
    for (int ct = 0; ct < 8; ct++) {
      f16x8 b = Bf[(kc * 8 + ct) * 64 + l];
      acc[ct] = __builtin_amdgcn_mfma_f32_16x16x32_f16(a, b, acc[ct], 0, 0, 0);
    }
  }
  // C/D layout: col=l&15, row=(l>>4)*4+j  [HW-verified m89].
  float sl = BIAS ? *slope : 0.f;
  f16* slab = ls + w * 16 * 128;
#pragma unroll
  for (int ct = 0; ct < 8; ct++) {
    float bv = BIAS ? bias[ct * 16 + l15] : 0.f;
#pragma unroll
    for (int j = 0; j < 4; j++) {
      float v = acc[ct][j];
      if (BIAS) {
        v += bv;
        v = v >= 0.f ? v : sl * v;
      }
      slab[(kgrp * 4 + j) * 128 + ct * 16 + l15] = (f16)v;
    }
  }
  __syncthreads();
  // Coalesced store: lane l -> row l>>2, chunks (l&3)+4i (16B each).
  {
    int r = l >> 2;
    int gnode = nodeBase + r;
    if (gnode < N) {
      const uint4* srcp = (const uint4*)(slab + r * 128);
      uint4* dstp = (uint4*)(out + (size_t)gnode * 128);
#pragma unroll
      for (int i = 0; i < 4; i++) {
        int chunk = (l & 3) + i * 4;
        dstp[chunk] = srcp[chunk];
      }
    }
  }
}

// Wide-gather pull aggregation: wave per dst node. 16 lanes/edge, 16B/lane
// (uint4 = 8 halfs): one instruction fetches 4 edge-rows (1KB). Lane l:
// edge-slot g=l>>4, feature-octet sub=l&15. fp32 accum[8]; shfl_xor reduce
// over g; lanes 0-15 apply self+bias+PReLU and write the 256B row.
template <bool POOL>
__global__ __launch_bounds__(256) void k_agg_v(const f16* __restrict__ hW,
                                               const int* __restrict__ rowptr,
                                               const int2* __restrict__ csr,
                                               const float* __restrict__ inv,
                                               const float* __restrict__ bias,
                                               const float* __restrict__ slope,
                                               const int* __restrict__ batch,
                                               f16* __restrict__ outh,
                                               float* __restrict__ pool,
                                               float* __restrict__ cntg, int N) {
  int wid = (blockIdx.x * 256 + threadIdx.x) >> 6;
  if (wid >= N) return;
  int l = threadIdx.x & 63;
  int g = l >> 4, sub = l & 15;
  int r0 = rowptr[wid], r1 = rowptr[wid + 1];
  float acc[8];
#pragma unroll
  for (int j = 0; j < 8; j++) acc[j] = 0.f;

  for (int base = r0; base < r1; base += 64) {
    int idx = base + l;
    int sl = 0;
    float cl = 0.f;
    if (idx < r1) {
      int2 e = csr[idx];
      sl = e.x;
      cl = __int_as_float(e.y);
    }
    int m = min(64, r1 - base);
    for (int k = 0; k < m; k += 32) {
      int nin = min(32, m - k);
      int ninstr = (nin + 3) >> 2;  // 1..8 gather instrs, 4 edges each
      uint4 v[8];
      float cc[8];
#pragma unroll
      for (int i = 0; i < 8; i++) {
        if (i < ninstr) {
          int ei = k + i * 4 + g;
          int ec = ei < m ? ei : m - 1;
          int s = __shfl(sl, ec);
          float c = __shfl(cl, ec);
          cc[i] = ei < m ? c : 0.f;
          v[i] = *(const uint4*)(hW + (size_t)s * 128 + sub * 8);
        }
      }
#pragma unroll
      for (int i = 0; i < 8; i++) {
        if (i < ninstr) {
          const __half2* hp = (const __half2*)&v[i];
#pragma unroll
          for (int j = 0; j < 4; j++) {
            float2 f = __half22float2(hp[j]);
            acc[2 * j] += f.x * cc[i];
            acc[2 * j + 1] += f.y * cc[i];
          }
        }
      }
    }
  }
  // reduce over the 4 edge-slot groups
#pragma unroll
  for (int off = 16; off < 64; off <<= 1)
#pragma unroll
    for (int j = 0; j < 8; j++) acc[j] += __shfl_xor(acc[j], off);

  if (l < 16) {  // g==0
    uint4 ov = *(const uint4*)(hW + (size_t)wid * 128 + sub * 8);
    const __half2* op = (const __half2*)&ov;
    float iv = inv[wid];
    float a = *slope;
    float res[8];
#pragma unroll
    for (int j = 0; j < 4; j++) {
      float2 f = __half22float2(op[j]);
      float2 b = *(const float2*)&bias[sub * 8 + j * 2];
      float vx = acc[2 * j] + f.x * iv + b.x;
      float vy = acc[2 * j + 1] + f.y * iv + b.y;
      res[2 * j] = vx >= 0.f ? vx : a * vx;
      res[2 * j + 1] = vy >= 0.f ? vy : a * vy;
    }
    if (POOL) {
      int gb = batch[wid];
#pragma unroll
      for (int j = 0; j < 8; j++)
        atomicAdd(&pool[(size_t)gb * 128 + sub * 8 + j], res[j]);
      if (sub == 0) atomicAdd(&cntg[gb], 1.0f);
    } else {
      uint4 q;
      __half2* qh = (__half2*)&q;
#pragma unroll
      for (int j = 0; j < 4; j++)
        qh[j] = __float22half2_rn(make_float2(res[2 * j], res[2 * j + 1]));
      *(uint4*)(outh + (size_t)wid * 128 + sub * 8) = q;
    }
  }
}

// Per-graph: mean, L2-normalize, out = hg @ fc2_w.T + fc2_b.  1 wave/graph.
__global__ __launch_bounds__(64) void k_final(const float* __restrict__ pool,
                                              const float* __restrict__ cntg,
                                              const float* __restrict__ fc2w,
                                              const float* __restrict__ fc2b,
                                              float* __restrict__ out) {
  __shared__ float hg[128];
  int g = blockIdx.x, l = threadIdx.x;
  float cnt = cntg[g];
  float ic = 1.0f / fmaxf(cnt, 1.0f);
  float2 v = *(const float2*)&pool[(size_t)g * 128 + l * 2];
  v.x *= ic;
  v.y *= ic;
  float ss = v.x * v.x + v.y * v.y;
#pragma unroll
  for (int off = 1; off < 64; off <<= 1) ss += __shfl_xor(ss, off);
  float nrm = sqrtf(ss);
  float sc = 1.0f / fmaxf(nrm, 1e-12f);
  hg[l * 2] = v.x * sc;
  hg[l * 2 + 1] = v.y * sc;
  __syncthreads();
  float acc = fc2b[l];
#pragma unroll 4
  for (int k = 0; k < 128; k++) acc += hg[k] * fc2w[l * 128 + k];
  out[(size_t)g * 64 + l] = acc;
}

extern "C" void kernel_launch(void* const* d_in, const int* in_sizes, int n_in,
                              void* d_out, int out_size, void* d_ws, size_t ws_size,
                              hipStream_t stream) {
  const float* x = (const float*)d_in[0];
  const int* ei = (const int*)d_in[1];
  const float* ew = (const float*)d_in[2];
  const int* batch = (const int*)d_in[3];
  const float* fc1_w = (const float*)d_in[4];
  const float* fc1_b = (const float*)d_in[5];
  const float* gc1_w = (const float*)d_in[6];
  const float* gc1_b = (const float*)d_in[7];
  const float* gc2_w = (const float*)d_in[8];
  const float* gc2_b = (const float*)d_in[9];
  const float* fc2_w = (const float*)d_in[10];
  const float* fc2_b = (const float*)d_in[11];
  const float* a_fc1 = (const float*)d_in[12];
  const float* a_gc1 = (const float*)d_in[13];
  const float* a_gc2 = (const float*)d_in[14];

  int N = in_sizes[0] / 128;
  int E = in_sizes[2];
  int G = out_size / 64;
  const int* src = ei;
  const int* dst = ei + E;

  char* p = (char*)d_ws;
  auto carve = [&](size_t bytes) -> char* {
    char* r = p;
    p += (bytes + 255) & ~(size_t)255;
    return r;
  };
  f16* bufA = (f16*)carve((size_t)N * 128 * 2);       // h (fp16 rows)
  f16* bufH = (f16*)carve((size_t)N * 128 * 2);       // hW (fp16 rows)
  int2* csr = (int2*)carve((size_t)E * 8);            // (src, coef-bits)
  int* cnt = (int*)carve((size_t)N * 4);
  int* rowptr = (int*)carve((size_t)(N + 1) * 4);
  int* cursor = (int*)carve((size_t)N * 4);
  float* degf = (float*)carve((size_t)N * 4);
  float* dis = (float*)carve((size_t)N * 4);
  float* inv = (float*)carve((size_t)N * 4);
  f16x8* Bf1 = (f16x8*)carve(2048 * 16);
  f16x8* Bf2 = (f16x8*)carve(2048 * 16);
  f16x8* Bf3 = (f16x8*)carve(2048 * 16);
  int NC = (N + CHK - 1) / CHK;
  int* chunkSum = (int*)carve((size_t)NC * 4);
  int* chunkOff = (int*)carve((size_t)NC * 4);
  float* pool = (float*)carve((size_t)G * 128 * 4);
  float* cntg = (float*)carve((size_t)G * 4);

  hipMemsetAsync(cnt, 0, (size_t)N * 4, stream);
  hipMemsetAsync(degf, 0, (size_t)N * 4, stream);
  hipMemsetAsync(pool, 0, (size_t)G * 128 * 4, stream);
  hipMemsetAsync(cntg, 0, (size_t)G * 4, stream);

  k_prep_bfrag<<<8, 256, 0, stream>>>(fc1_w, Bf1);
  k_prep_bfrag<<<8, 256, 0, stream>>>(gc1_w, Bf2);
  k_prep_bfrag<<<8, 256, 0, stream>>>(gc2_w, Bf3);

  int gE = (E + 255) / 256;
  int gN = (N + 255) / 256;
  k_hist<<<gE, 256, 0, stream>>>(dst, ew, cnt, degf, E);
  k_dis<<<gN, 256, 0, stream>>>(degf, dis, inv, N);
  k_scan_reduce<<<NC, 256, 0, stream>>>(cnt, chunkSum, N);
  k_scan_chunks<<<1, 64, 0, stream>>>(chunkSum, chunkOff, NC);
  k_scan_final<<<NC, 256, 0, stream>>>(cnt, chunkOff, rowptr, cursor, N, E);
  k_scatter<<<gE, 256, 0, stream>>>(src, dst, ew, dis, cursor, csr, E);

  int gGemm = (N + 63) / 64;
  int gAgg = (int)(((size_t)N * 64 + 255) / 256);

  // h1 = prelu(x @ fc1_w.T + fc1_b) -> bufA (fp16)
  k_gemm_mfma<true, true><<<gGemm, 256, 0, stream>>>(nullptr, x, Bf1, bufA, fc1_b, a_fc1, N);
  // conv1: hW = h @ gc1_w.T -> bufH ; wide-gather aggregate -> bufA
  k_gemm_mfma<false, false><<<gGemm, 256, 0, stream>>>(bufA, nullptr, Bf2, bufH, nullptr, nullptr, N);
  k_agg_v<false><<<gAgg, 256, 0, stream>>>(bufH, rowptr, csr, inv, gc1_b, a_gc1, batch,
                                           bufA, nullptr, cntg, N);
  // conv2: hW = h @ gc2_w.T -> bufH ; aggregate + pool (fused)
  k_gemm_mfma<false, false><<<gGemm, 256, 0, stream>>>(bufA, nullptr, Bf3, bufH, nullptr, nullptr, N);
  k_agg_v<true><<<gAgg, 256, 0, stream>>>(bufH, rowptr, csr, inv, gc2_b, a_gc2, batch,
                                          nullptr, pool, cntg, N);
  k_final<<<G, 64, 0, stream>>>(pool, cntg, fc2_w, fc2_b, (float*)d_out);
}

// Round 8
// 608.002 us; speedup vs baseline: 1.8694x; 1.4884x over previous
//
#include <hip/hip_runtime.h>
#include <hip/hip_fp16.h>

// GNN: fc1 -> GCNConv x2 -> mean-pool -> L2norm -> fc2
// N=100000, E=1.6M, F=H=128, O=64, G=1024.
// R8: revert aggregation to R5's proven structure (wave/node, reg-held CSR +
// shfl broadcast, 256B fp16 row gathers, fused contiguous-lane pool atomics)
// with gather depth 8 -> 16 in flight. MFMA GEMMs unchanged.
// Evidence so far: agg time tracks random 64B-line count (6.4M/conv) —
// fp32->fp16 halved lines (297->235us), 4x-wider instrs changed nothing.

#define CHK 1024  // scan chunk size
typedef unsigned int u32;
using f16 = _Float16;
using f16x8 = __attribute__((ext_vector_type(8))) _Float16;
using f32x4 = __attribute__((ext_vector_type(4))) float;

__global__ __launch_bounds__(256) void k_hist(const int* __restrict__ dst,
                                              const float* __restrict__ w,
                                              int* __restrict__ cnt,
                                              float* __restrict__ degf, int E) {
  int e = blockIdx.x * 256 + threadIdx.x;
  if (e < E) {
    int d = dst[e];
    atomicAdd(&cnt[d], 1);
    atomicAdd(&degf[d], w[e]);
  }
}

__global__ __launch_bounds__(256) void k_dis(const float* __restrict__ degf,
                                             float* __restrict__ dis,
                                             float* __restrict__ inv, int N) {
  int n = blockIdx.x * 256 + threadIdx.x;
  if (n < N) {
    float deg = degf[n] + 1.0f;  // self-loop weight 1
    dis[n] = rsqrtf(deg);
    inv[n] = 1.0f / deg;
  }
}

__global__ __launch_bounds__(256) void k_scan_reduce(const int* __restrict__ cnt,
                                                     int* __restrict__ chunkSum, int N) {
  __shared__ int sd[256];
  int b = blockIdx.x, t = threadIdx.x;
  int base = b * CHK + t * 4;
  int s = 0;
#pragma unroll
  for (int i = 0; i < 4; i++)
    if (base + i < N) s += cnt[base + i];
  sd[t] = s;
  __syncthreads();
  for (int off = 128; off; off >>= 1) {
    if (t < off) sd[t] += sd[t + off];
    __syncthreads();
  }
  if (t == 0) chunkSum[b] = sd[0];
}

__global__ void k_scan_chunks(const int* __restrict__ chunkSum,
                              int* __restrict__ chunkOff, int NC) {
  if (threadIdx.x == 0 && blockIdx.x == 0) {
    int s = 0;
    for (int i = 0; i < NC; i++) {
      chunkOff[i] = s;
      s += chunkSum[i];
    }
  }
}

__global__ __launch_bounds__(256) void k_scan_final(const int* __restrict__ cnt,
                                                    const int* __restrict__ chunkOff,
                                                    int* __restrict__ rowptr,
                                                    int* __restrict__ cursor, int N, int E) {
  __shared__ int sd[256];
  int b = blockIdx.x, t = threadIdx.x;
  int base = b * CHK + t * 4;
  int v[4], loc[4];
#pragma unroll
  for (int i = 0; i < 4; i++) v[i] = (base + i < N) ? cnt[base + i] : 0;
  loc[0] = 0;
  loc[1] = v[0];
  loc[2] = v[0] + v[1];
  loc[3] = v[0] + v[1] + v[2];
  int tot = loc[3] + v[3];
  sd[t] = tot;
  __syncthreads();
  for (int off = 1; off < 256; off <<= 1) {
    int xv = (t >= off) ? sd[t - off] : 0;
    __syncthreads();
    sd[t] += xv;
    __syncthreads();
  }
  int tbase = (t ? sd[t - 1] : 0) + chunkOff[b];
#pragma unroll
  for (int i = 0; i < 4; i++) {
    if (base + i < N) {
      int r = tbase + loc[i];
      rowptr[base + i] = r;
      cursor[base + i] = r;
    }
  }
  if (b == 0 && t == 0) rowptr[N] = E;
}

// CSR by dst: entry = (src, coef-bits)
__global__ __launch_bounds__(256) void k_scatter(const int* __restrict__ src,
                                                 const int* __restrict__ dst,
                                                 const float* __restrict__ w,
                                                 const float* __restrict__ dis,
                                                 int* __restrict__ cursor,
                                                 int2* __restrict__ csr, int E) {
  int e = blockIdx.x * 256 + threadIdx.x;
  if (e < E) {
    int s = src[e], d = dst[e];
    float c = w[e] * dis[s] * dis[d];
    int p = atomicAdd(&cursor[d], 1);
    int2 v;
    v.x = s;
    v.y = __float_as_int(c);
    csr[p] = v;
  }
}

// Pack W [128][128] row-major (W[o][k], fp32) into MFMA B-fragment order.
__global__ __launch_bounds__(256) void k_prep_bfrag(const float* __restrict__ W,
                                                    f16x8* __restrict__ Bf) {
  int t = blockIdx.x * 256 + threadIdx.x;  // 0..2047
  int combo = t >> 6;                      // kc*8+ct
  int l = t & 63;
  int o = (combo & 7) * 16 + (l & 15);
  int k0 = (combo >> 3) * 32 + (l >> 4) * 8;
  f16x8 b;
#pragma unroll
  for (int i = 0; i < 8; i++) b[i] = (f16)W[o * 128 + k0 + i];
  Bf[combo * 64 + l] = b;
}

// MFMA GEMM: out[n][o] = act( sum_k A[n][k]*W[o][k] (+bias) ).
template <bool FP32_IN, bool BIAS>
__global__ __launch_bounds__(256) void k_gemm_mfma(const f16* __restrict__ Ah,
                                                   const float* __restrict__ Af,
                                                   const f16x8* __restrict__ Bf,
                                                   f16* __restrict__ out,
                                                   const float* __restrict__ bias,
                                                   const float* __restrict__ slope,
                                                   int N) {
  __shared__ f16 ls[64 * 128];
  int t = threadIdx.x;
  int w = t >> 6, l = t & 63;
  int l15 = l & 15, kgrp = l >> 4;
  int nodeBase = blockIdx.x * 64 + w * 16;
  f32x4 acc[8];
#pragma unroll
  for (int ct = 0; ct < 8; ct++)
#pragma unroll
    for (int j = 0; j < 4; j++) acc[ct][j] = 0.f;

  int arow = nodeBase + l15;
  if (arow >= N) arow = N - 1;  // clamp: duplicate read, store is guarded
#pragma unroll
  for (int kc = 0; kc < 4; kc++) {
    f16x8 a;
    if (FP32_IN) {
      const float4* p0 = (const float4*)(Af + (size_t)arow * 128 + kc * 32 + kgrp * 8);
      float4 x0 = p0[0], x1 = p0[1];
      a[0] = (f16)x0.x; a[1] = (f16)x0.y; a[2] = (f16)x0.z; a[3] = (f16)x0.w;
      a[4] = (f16)x1.x; a[5] = (f16)x1.y; a[6] = (f16)x1.z; a[7] = (f16)x1.w;
    } else {
      a = *(const f16x8*)(Ah + (size_t)arow * 128 + kc * 32 + kgrp * 8);
    }
#pragma unroll
    for (int ct = 0; ct < 8; ct++) {
      f16x8 b = Bf[(kc * 8 + ct) * 64 + l];
      acc[ct] = __builtin_amdgcn_mfma_f32_16x16x32_f16(a, b, acc[ct], 0, 0, 0);
    }
  }
  // C/D layout: col=l&15, row=(l>>4)*4+j  [HW-verified m89].
  float sl = BIAS ? *slope : 0.f;
  f16* slab = ls + w * 16 * 128;
#pragma unroll
  for (int ct = 0; ct < 8; ct++) {
    float bv = BIAS ? bias[ct * 16 + l15] : 0.f;
#pragma unroll
    for (int j = 0; j < 4; j++) {
      float v = acc[ct][j];
      if (BIAS) {
        v += bv;
        v = v >= 0.f ? v : sl * v;
      }
      slab[(kgrp * 4 + j) * 128 + ct * 16 + l15] = (f16)v;
    }
  }
  __syncthreads();
  // Coalesced store: lane l -> row l>>2, chunks (l&3)+4i (16B each).
  {
    int r = l >> 2;
    int gnode = nodeBase + r;
    if (gnode < N) {
      const uint4* srcp = (const uint4*)(slab + r * 128);
      uint4* dstp = (uint4*)(out + (size_t)gnode * 128);
#pragma unroll
      for (int i = 0; i < 4; i++) {
        int chunk = (l & 3) + i * 4;
        dstp[chunk] = srcp[chunk];
      }
    }
  }
}

// Pull aggregation (R5 structure, depth 16): wave per dst node; hW fp16 rows
// (64 half2); reg-held CSR (int2) + shfl broadcast; 16 gathers in flight;
// fp32 accum. !POOL: write fp16 row. POOL: contiguous-lane fp32 pool atomics
// (64 lanes x 2 adjacent floats -> HW merges 8 lanes/line).
template <bool POOL>
__global__ __launch_bounds__(256) void k_agg_h(const __half2* __restrict__ hW,
                                               const int* __restrict__ rowptr,
                                               const int2* __restrict__ csr,
                                               const float* __restrict__ inv,
                                               const float* __restrict__ bias,
                                               const float* __restrict__ slope,
                                               const int* __restrict__ batch,
                                               __half2* __restrict__ outh,
                                               float* __restrict__ pool,
                                               float* __restrict__ cntg, int N) {
  int wid = (blockIdx.x * 256 + threadIdx.x) >> 6;
  if (wid >= N) return;
  int l = threadIdx.x & 63;
  int r0 = rowptr[wid], r1 = rowptr[wid + 1];
  float2 acc;
  {
    float2 f = __half22float2(hW[(size_t)wid * 64 + l]);
    float iv = inv[wid];
    acc.x = f.x * iv;
    acc.y = f.y * iv;
  }
  for (int base = r0; base < r1; base += 64) {
    int idx = base + l;
    int sl = 0;
    float cl = 0.f;
    if (idx < r1) {
      int2 e = csr[idx];
      sl = e.x;
      cl = __int_as_float(e.y);
    }
    int m = min(64, r1 - base);
    for (int k = 0; k < m; k += 16) {  // k in {0,16,32,48}; k+i <= 63
      __half2 v[16];
      float c[16];
#pragma unroll
      for (int i = 0; i < 16; i++) {
        int s = __shfl(sl, k + i);
        c[i] = __shfl(cl, k + i);
        v[i] = hW[(size_t)s * 64 + l];  // OOB edges: s=0,c=0 -> harmless hot line
      }
#pragma unroll
      for (int i = 0; i < 16; i++) {
        float2 f = __half22float2(v[i]);
        acc.x += f.x * c[i];
        acc.y += f.y * c[i];
      }
    }
  }
  float a = *slope;
  float2 b = *(const float2*)&bias[l * 2];
  acc.x += b.x;
  acc.y += b.y;
  acc.x = acc.x >= 0.f ? acc.x : a * acc.x;
  acc.y = acc.y >= 0.f ? acc.y : a * acc.y;
  if (POOL) {
    int g = batch[wid];
    atomicAdd(&pool[(size_t)g * 128 + l * 2], acc.x);
    atomicAdd(&pool[(size_t)g * 128 + l * 2 + 1], acc.y);
    if (l == 0) atomicAdd(&cntg[g], 1.0f);
  } else {
    outh[(size_t)wid * 64 + l] = __float22half2_rn(acc);
  }
}

// Per-graph: mean, L2-normalize, out = hg @ fc2_w.T + fc2_b.  1 wave/graph.
__global__ __launch_bounds__(64) void k_final(const float* __restrict__ pool,
                                              const float* __restrict__ cntg,
                                              const float* __restrict__ fc2w,
                                              const float* __restrict__ fc2b,
                                              float* __restrict__ out) {
  __shared__ float hg[128];
  int g = blockIdx.x, l = threadIdx.x;
  float cnt = cntg[g];
  float ic = 1.0f / fmaxf(cnt, 1.0f);
  float2 v = *(const float2*)&pool[(size_t)g * 128 + l * 2];
  v.x *= ic;
  v.y *= ic;
  float ss = v.x * v.x + v.y * v.y;
#pragma unroll
  for (int off = 1; off < 64; off <<= 1) ss += __shfl_xor(ss, off);
  float nrm = sqrtf(ss);
  float sc = 1.0f / fmaxf(nrm, 1e-12f);
  hg[l * 2] = v.x * sc;
  hg[l * 2 + 1] = v.y * sc;
  __syncthreads();
  float acc = fc2b[l];
#pragma unroll 4
  for (int k = 0; k < 128; k++) acc += hg[k] * fc2w[l * 128 + k];
  out[(size_t)g * 64 + l] = acc;
}

extern "C" void kernel_launch(void* const* d_in, const int* in_sizes, int n_in,
                              void* d_out, int out_size, void* d_ws, size_t ws_size,
                              hipStream_t stream) {
  const float* x = (const float*)d_in[0];
  const int* ei = (const int*)d_in[1];
  const float* ew = (const float*)d_in[2];
  const int* batch = (const int*)d_in[3];
  const float* fc1_w = (const float*)d_in[4];
  const float* fc1_b = (const float*)d_in[5];
  const float* gc1_w = (const float*)d_in[6];
  const float* gc1_b = (const float*)d_in[7];
  const float* gc2_w = (const float*)d_in[8];
  const float* gc2_b = (const float*)d_in[9];
  const float* fc2_w = (const float*)d_in[10];
  const float* fc2_b = (const float*)d_in[11];
  const float* a_fc1 = (const float*)d_in[12];
  const float* a_gc1 = (const float*)d_in[13];
  const float* a_gc2 = (const float*)d_in[14];

  int N = in_sizes[0] / 128;
  int E = in_sizes[2];
  int G = out_size / 64;
  const int* src = ei;
  const int* dst = ei + E;

  char* p = (char*)d_ws;
  auto carve = [&](size_t bytes) -> char* {
    char* r = p;
    p += (bytes + 255) & ~(size_t)255;
    return r;
  };
  f16* bufA = (f16*)carve((size_t)N * 128 * 2);       // h (fp16 rows)
  f16* bufH = (f16*)carve((size_t)N * 128 * 2);       // hW (fp16 rows)
  int2* csr = (int2*)carve((size_t)E * 8);            // (src, coef-bits)
  int* cnt = (int*)carve((size_t)N * 4);
  int* rowptr = (int*)carve((size_t)(N + 1) * 4);
  int* cursor = (int*)carve((size_t)N * 4);
  float* degf = (float*)carve((size_t)N * 4);
  float* dis = (float*)carve((size_t)N * 4);
  float* inv = (float*)carve((size_t)N * 4);
  f16x8* Bf1 = (f16x8*)carve(2048 * 16);
  f16x8* Bf2 = (f16x8*)carve(2048 * 16);
  f16x8* Bf3 = (f16x8*)carve(2048 * 16);
  int NC = (N + CHK - 1) / CHK;
  int* chunkSum = (int*)carve((size_t)NC * 4);
  int* chunkOff = (int*)carve((size_t)NC * 4);
  float* pool = (float*)carve((size_t)G * 128 * 4);
  float* cntg = (float*)carve((size_t)G * 4);

  hipMemsetAsync(cnt, 0, (size_t)N * 4, stream);
  hipMemsetAsync(degf, 0, (size_t)N * 4, stream);
  hipMemsetAsync(pool, 0, (size_t)G * 128 * 4, stream);
  hipMemsetAsync(cntg, 0, (size_t)G * 4, stream);

  k_prep_bfrag<<<8, 256, 0, stream>>>(fc1_w, Bf1);
  k_prep_bfrag<<<8, 256, 0, stream>>>(gc1_w, Bf2);
  k_prep_bfrag<<<8, 256, 0, stream>>>(gc2_w, Bf3);

  int gE = (E + 255) / 256;
  int gN = (N + 255) / 256;
  k_hist<<<gE, 256, 0, stream>>>(dst, ew, cnt, degf, E);
  k_dis<<<gN, 256, 0, stream>>>(degf, dis, inv, N);
  k_scan_reduce<<<NC, 256, 0, stream>>>(cnt, chunkSum, N);
  k_scan_chunks<<<1, 64, 0, stream>>>(chunkSum, chunkOff, NC);
  k_scan_final<<<NC, 256, 0, stream>>>(cnt, chunkOff, rowptr, cursor, N, E);
  k_scatter<<<gE, 256, 0, stream>>>(src, dst, ew, dis, cursor, csr, E);

  int gGemm = (N + 63) / 64;
  int gAgg = (int)(((size_t)N * 64 + 255) / 256);

  // h1 = prelu(x @ fc1_w.T + fc1_b) -> bufA (fp16)
  k_gemm_mfma<true, true><<<gGemm, 256, 0, stream>>>(nullptr, x, Bf1, bufA, fc1_b, a_fc1, N);
  // conv1: hW = h @ gc1_w.T -> bufH ; aggregate -> bufA
  k_gemm_mfma<false, false><<<gGemm, 256, 0, stream>>>(bufA, nullptr, Bf2, bufH, nullptr, nullptr, N);
  k_agg_h<false><<<gAgg, 256, 0, stream>>>((const __half2*)bufH, rowptr, csr, inv, gc1_b,
                                           a_gc1, batch, (__half2*)bufA, nullptr, cntg, N);
  // conv2: hW = h @ gc2_w.T -> bufH ; aggregate + pool (fused)
  k_gemm_mfma<false, false><<<gGemm, 256, 0, stream>>>(bufA, nullptr, Bf3, bufH, nullptr, nullptr, N);
  k_agg_h<true><<<gAgg, 256, 0, stream>>>((const __half2*)bufH, rowptr, csr, inv, gc2_b,
                                          a_gc2, batch, nullptr, pool, cntg, N);
  k_final<<<G, 64, 0, stream>>>(pool, cntg, fc2_w, fc2_b, (float*)d_out);
}